// Round 4
// baseline (211.637 us; speedup 1.0000x reference)
//
#include <hip/hip_runtime.h>

// CTC batch cost (Keras ctc_batch_cost, full lengths).
// B=64, T=2048, C=128 (blank=127), L=256, S=513.
//
// Round-16: DROP LDS ENTIRELY — direct per-lane global gathers.
// Evidence: R12/R13/R14/R15 (four different structures: unrolled, 2-wave,
// rolled, asm-ds_read+counted-lgkm) all pin at ~240 cyc/step while VALU
// busy VARIES (R14 -10% busy, same time) -> not issue-bound; and
// SQ_LDS_BANK_CONFLICT is bit-identical (1,889,381) in every round. The
// only shared subsystem is the LDS gather path (DMA staging + random-column
// ds_read with ~3.6 conflict-cyc/gather + in-order lgkm). This round
// removes it: all 5 gathers of a step live in ONE 512 B row, so per-lane
// global_load_dword with compile-time offset: immediates touches <=8
// sectors of a single row per instruction (L1-resident, conflict-free).
//  - G g[8] lookahead (40 outstanding dwords; compiler emits counted
//    vmcnt waits for visible loads — no DMA aliasing possible now).
//  - 5 per-lane column pointers advance +-4KB once per 8-step group
//    (10 VALU / 8 steps); fill offsets are s*C_ compile-time imms.
//  - blank column pointer is wave-uniform -> compiler uses scalar loads.
//  - LDS use shrinks to a 2.5 KB fwd/bwd transfer buffer.
// Numerics bit-identical to R13/R15: deferred-EPS (raw loads, +EPSF at
// use), block-float linear mantissas, exponent renorm every 4 steps with
// DPP neighbor adoption, fwd/bwd meet at t=1023/1024, 9-FMA dot +
// 64-lane logsumexp.

#define B_ 64
#define T_ 2048
#define C_ 128
#define L_ 256
#define BLANK_ (C_ - 1)
#define EPSF 1e-7f
#define LN2F 0.69314718055994530942f
#define SENT_ (-(1 << 28))    // "lane is all-zero" exponent sentinel

// lane l -> value of lane l-1; lane 0 -> 0. DPP ctrl 0x138 = wave_shr:1.
__device__ __forceinline__ float dpp_shr1_f(float x) {
    return __int_as_float(
        __builtin_amdgcn_update_dpp(0, __float_as_int(x), 0x138, 0xf, 0xf, false));
}
__device__ __forceinline__ int dpp_shr1_i(int x) {
    return __builtin_amdgcn_update_dpp(0, x, 0x138, 0xf, 0xf, false);
}
// lane l -> value of lane l+1; lane 63 -> 0. DPP ctrl 0x130 = wave_shl:1.
__device__ __forceinline__ float dpp_shl1_f(float x) {
    return __int_as_float(
        __builtin_amdgcn_update_dpp(0, __float_as_int(x), 0x130, 0xf, 0xf, false));
}
__device__ __forceinline__ int dpp_shl1_i(int x) {
    return __builtin_amdgcn_update_dpp(0, x, 0x130, 0xf, 0xf, false);
}

struct G { float pb, p1, p3, p5, p7; };  // RAW values (EPSF added at use)

__launch_bounds__(128, 1)
__global__ void ctc_loss_kernel(const int* __restrict__ y_true,
                                const float* __restrict__ y_pred,
                                float* __restrict__ out) {
    const int b = blockIdx.x;
    const int tid = threadIdx.x;
    const int w = __builtin_amdgcn_readfirstlane(tid >> 6);  // 0=fwd, 1=bwd
    const int l = tid & 63;

    __shared__ float xfer[640];  // bwd -> fwd handoff (9 states + E) x 64

    const int* __restrict__ lab = y_true + b * L_;
    const int4 lv = *(const int4*)(lab + 4 * l);   // labels 4l..4l+3
    const int e1 = lv.x, e3 = lv.y, e5 = lv.z, e7 = lv.w;
    const int em1 = (l > 0) ? lab[4 * l - 1] : -1;
    const float m1f = ((l > 0) && (e1 != em1)) ? 1.0f : 0.0f;  // skip gates
    const float m3f = (e3 != e1) ? 1.0f : 0.0f;
    const float m5f = (e5 != e3) ? 1.0f : 0.0f;
    const float m7f = (e7 != e5) ? 1.0f : 0.0f;
    const float m8f = (l == 63) ? 1.0f : 0.0f;     // state-512 coupling gate

    const float* __restrict__ base = y_pred + (size_t)b * (T_ * C_);

    // Per-lane column pointers (pB is wave-uniform -> scalar loads).
    const float* pB;
    const float* q1;
    const float* q3;
    const float* q5;
    const float* q7;

    G g[8];  // lookahead-8 slots; slot index always compile-time
    auto fill = [&](int s, int off) {  // off in floats, compile-time imm
        g[s].pb = pB[off];
        g[s].p1 = q1[off];
        g[s].p3 = q3[off];
        g[s].p5 = q5[off];
        g[s].p7 = q7[off];
    };
    auto adv = [&](int d) { pB += d; q1 += d; q3 += d; q5 += d; q7 += d; };

    // linear mantissas at lane-local scale 2^E
    float a0 = 0.f, a1 = 0.f, a2 = 0.f, a3 = 0.f, a4 = 0.f,
          a5 = 0.f, a6 = 0.f, a7 = 0.f, a8 = 0.f;
    int E = SENT_;
    float upscale = 1.0f;  // 2^(E_nbr - E), fixed within a 4-step window

    // ---------------- forward machinery (wave 0) ----------------
    auto step = [&](const G& q) {
        const float pb = q.pb + EPSF, p1 = q.p1 + EPSF, p3 = q.p3 + EPSF,
                    p5 = q.p5 + EPSF, p7 = q.p7 + EPSF;
        const float up = dpp_shr1_f(a7) * upscale;  // state 8l-1, rescaled
        const float n0 = (a0 + up) * pb;
        const float n1 = fmaf(m1f, up, a0 + a1) * p1;
        const float n2 = (a1 + a2) * pb;
        const float n3 = fmaf(m3f, a1, a2 + a3) * p3;
        const float n4 = (a3 + a4) * pb;
        const float n5 = fmaf(m5f, a3, a4 + a5) * p5;
        const float n6 = (a5 + a6) * pb;
        const float n7 = fmaf(m7f, a5, a6 + a7) * p7;
        const float n8 = fmaf(m8f, a7, a8) * pb;    // state 512
        a0 = n0; a1 = n1; a2 = n2; a3 = n3; a4 = n4;
        a5 = n5; a6 = n6; a7 = n7; a8 = n8;
    };

    auto boundary = [&]() {
        float mx = fmaxf(fmaxf(fmaxf(a0, a1), fmaxf(a2, a3)),
                         fmaxf(fmaxf(a4, a5), fmaxf(a6, a7)));
        mx = fmaxf(mx, a8);
        const bool z = (mx == 0.0f);
        const int e = (int)(__float_as_uint(mx) >> 23) - 127;
        const float s = z ? 1.0f : __uint_as_float((unsigned)(127 - e) << 23);
        a0 *= s; a1 *= s; a2 *= s; a3 *= s; a4 *= s;
        a5 *= s; a6 *= s; a7 *= s; a8 *= s;
        E = z ? SENT_ : (E + e);
        int upE = dpp_shr1_i(E);
        if (l == 0) upE = SENT_;
        if (E == SENT_) E = upE;            // adopt neighbor scale (exact)
        int d = upE - E;
        d = min(max(d, -126), 120);
        upscale = __uint_as_float((unsigned)(d + 127) << 23);
    };

    // ---------------- backward machinery (wave 1) ----------------
    auto stepb = [&](const G& q) {
        const float pb = q.pb + EPSF, p1 = q.p1 + EPSF, p3 = q.p3 + EPSF,
                    p5 = q.p5 + EPSF, p7 = q.p7 + EPSF;
        const float d0 = a0 * pb, d1 = a1 * p1, d2 = a2 * pb,
                    d3 = a3 * p3, d4 = a4 * pb, d5 = a5 * p5,
                    d6 = a6 * pb, d7 = a7 * p7, d8 = a8 * pb;
        const float u = fmaf(m1f, d1, d0);          // exported to lane l-1
        const float dn = dpp_shl1_f(u) * upscale;   // lane l+1's u, rescaled
        a0 = d0 + d1;
        a1 = fmaf(m3f, d3, d1 + d2);
        a2 = d2 + d3;
        a3 = fmaf(m5f, d5, d3 + d4);
        a4 = d4 + d5;
        a5 = fmaf(m7f, d7, d5 + d6);
        a6 = d6 + d7;
        a7 = fmaf(m8f, d8, d7 + dn);                // state 511 (+512 on l=63)
        a8 = d8;                                    // state 512
    };

    auto boundaryb = [&]() {
        float mx = fmaxf(fmaxf(fmaxf(a0, a1), fmaxf(a2, a3)),
                         fmaxf(fmaxf(a4, a5), fmaxf(a6, a7)));
        mx = fmaxf(mx, a8);
        const bool z = (mx == 0.0f);
        const int e = (int)(__float_as_uint(mx) >> 23) - 127;
        const float s = z ? 1.0f : __uint_as_float((unsigned)(127 - e) << 23);
        a0 *= s; a1 *= s; a2 *= s; a3 *= s; a4 *= s;
        a5 *= s; a6 *= s; a7 *= s; a8 *= s;
        E = z ? SENT_ : (E + e);
        int upE = dpp_shl1_i(E);            // neighbor is lane l+1
        if (l == 63) upE = SENT_;
        if (E == SENT_) E = upE;
        int d = upE - E;
        d = min(max(d, -126), 120);
        upscale = __uint_as_float((unsigned)(d + 127) << 23);
    };

    if (w == 0) {
        // ======== forward: init row 0, steps t = 1..1023 ========
        pB = base + BLANK_; q1 = base + e1; q3 = base + e3;
        q5 = base + e5; q7 = base + e7;
#pragma unroll
        for (int s = 0; s < 8; ++s) fill(s, s * C_);   // rows 0..7
        if (l == 0) { a0 = g[0].pb + EPSF; a1 = g[0].p1 + EPSF; E = 0; }
        boundary();                        // seeds lane1's adoption of E
        adv(8 * C_);                       // base -> row 8
        fill(0, 0);                        // slot 0 <- row 8
#pragma unroll
        for (int s = 1; s < 8; ++s) {      // t = 1..7
            step(g[s]); fill(s, s * C_);   // refill rows 9..15
            if ((s & 3) == 3) boundary();
        }
#pragma unroll 1
        for (int m = 1; m <= 126; ++m) {   // t = 8..1015
            adv(8 * C_);                   // base -> row 8m+8
#pragma unroll
            for (int s = 0; s < 8; ++s) {
                step(g[s]); fill(s, s * C_);
                if ((s & 3) == 3) boundary();
            }
        }
#pragma unroll
        for (int s = 0; s < 8; ++s) {      // t = 1016..1023, no fills
            step(g[s]);
            if ((s & 3) == 3) boundary();
        }
        // a0..a8, E now hold alpha_{1023}
    } else {
        // ======== backward: init c_2048 = f, steps q = 0..1023 ========
        const float* bb = base + 2047 * C_;
        pB = bb + BLANK_; q1 = bb + e1; q3 = bb + e3;
        q5 = bb + e5; q7 = bb + e7;
#pragma unroll
        for (int s = 0; s < 8; ++s) fill(s, -(s * C_));  // rows 2047..2040
        if (l == 63) { a7 = 1.0f; a8 = 1.0f; E = 0; }
        boundaryb();                       // seeds lane62's adoption of E
#pragma unroll 1
        for (int m = 0; m <= 126; ++m) {   // q = 0..1015
            adv(-8 * C_);                  // base -> row 2039-8m
#pragma unroll
            for (int s = 0; s < 8; ++s) {
                stepb(g[s]); fill(s, -(s * C_));   // refill rows 2039-8m-s
                if ((s & 3) == 3) boundaryb();
            }
        }
#pragma unroll
        for (int s = 0; s < 8; ++s) {      // q = 1016..1023, no fills
            stepb(g[s]);
            if ((s & 3) == 3) boundaryb();
        }
        // a0..a8, E now hold c_{1024}; export
        xfer[0 * 64 + l] = a0; xfer[1 * 64 + l] = a1; xfer[2 * 64 + l] = a2;
        xfer[3 * 64 + l] = a3; xfer[4 * 64 + l] = a4; xfer[5 * 64 + l] = a5;
        xfer[6 * 64 + l] = a6; xfer[7 * 64 + l] = a7; xfer[8 * 64 + l] = a8;
        ((int*)xfer)[9 * 64 + l] = E;
    }

    __syncthreads();

    if (w == 0) {
        // p = <alpha_{1023}, c_{1024}>: lane dot then 64-lane logsumexp.
        float sd = a0 * xfer[0 * 64 + l];
        sd = fmaf(a1, xfer[1 * 64 + l], sd);
        sd = fmaf(a2, xfer[2 * 64 + l], sd);
        sd = fmaf(a3, xfer[3 * 64 + l], sd);
        sd = fmaf(a4, xfer[4 * 64 + l], sd);
        sd = fmaf(a5, xfer[5 * 64 + l], sd);
        sd = fmaf(a6, xfer[6 * 64 + l], sd);
        sd = fmaf(a7, xfer[7 * 64 + l], sd);
        sd = fmaf(a8, xfer[8 * 64 + l], sd);
        const int E2 = ((const int*)xfer)[9 * 64 + l];
        const bool nz = (sd > 0.0f);
        int Es = nz ? (E + E2) : SENT_;
        int M = Es;
#pragma unroll
        for (int o = 32; o; o >>= 1) M = max(M, __shfl_xor(M, o));
        int d = Es - M;
        d = max(d, -126);
        float val = nz ? sd * __uint_as_float((unsigned)(d + 127) << 23) : 0.0f;
#pragma unroll
        for (int o = 32; o; o >>= 1) val += __shfl_xor(val, o);
        if (l == 0) out[b] = -(__logf(val) + (float)M * LN2F);
    }
}

extern "C" void kernel_launch(void* const* d_in, const int* in_sizes, int n_in,
                              void* d_out, int out_size, void* d_ws, size_t ws_size,
                              hipStream_t stream) {
    const int* y_true = (const int*)d_in[0];
    const float* y_pred = (const float*)d_in[1];
    float* out = (float*)d_out;
    ctc_loss_kernel<<<B_, 128, 0, stream>>>(y_true, y_pred, out);
}